// Round 1
// baseline (422.658 us; speedup 1.0000x reference)
//
#include <hip/hip_runtime.h>

#define SLEN 2048
#define NB 2
#define NHQ 32
#define NHK 8
#define DH 128
#define QBLK 64
#define KVBLK 64
#define NWAVES 4
#define VSTR 72      // Vt row stride in bf16 elems (144B, 16B-aligned, bank-spread)
#define PSTR 72      // P row stride in bf16 elems

typedef float  f32x4  __attribute__((ext_vector_type(4)));
typedef short  bf16x8 __attribute__((ext_vector_type(8)));
typedef short  bf16x4 __attribute__((ext_vector_type(4)));

__device__ __forceinline__ unsigned short f2bf(float f) {
  union { float f; unsigned int u; } v; v.f = f;
  unsigned int r = (v.u + 0x7fffu + ((v.u >> 16) & 1u)) >> 16;
  return (unsigned short)r;
}

__global__ __launch_bounds__(256, 2)
void fattn_fwd(const float* __restrict__ Q, const float* __restrict__ K,
               const float* __restrict__ V, float* __restrict__ O) {
  const int tid  = threadIdx.x;
  const int w    = tid >> 6;        // wave 0..3
  const int lane = tid & 63;
  const int l15  = lane & 15;
  const int g    = lane >> 4;       // 16-lane group 0..3

  const int qt = (int)gridDim.x - 1 - (int)blockIdx.x;  // big tiles dispatch first
  const int hb = blockIdx.y;        // 0..63
  const int b  = hb >> 5;
  const int h  = hb & (NHQ - 1);
  const int kh = h >> 2;            // GQA group (repeat_interleave)

  const int qb = qt * QBLK;
  const int qw = qb + 16 * w;       // this wave's first q row

  __shared__ alignas(16) unsigned short Klds[KVBLK * DH];          // 16 KB, XOR-swizzled rows
  __shared__ alignas(16) unsigned short Vt[DH * VSTR];             // 18 KB, V transposed
  __shared__ alignas(16) unsigned short Plds[NWAVES][16 * PSTR];   // 9 KB, wave-private

  // ---- Q fragments: direct global -> reg (read once) ----
  const float* qp = Q + ((size_t)((qb + 16 * w + l15) * NB + b) * NHQ + h) * DH;
  bf16x8 qa[4];
#pragma unroll
  for (int s = 0; s < 4; ++s) {
    const float* p = qp + 32 * s + 8 * g;
    float4 f0 = *(const float4*)(p);
    float4 f1 = *(const float4*)(p + 4);
    bf16x8 a;
    a[0] = (short)f2bf(f0.x); a[1] = (short)f2bf(f0.y);
    a[2] = (short)f2bf(f0.z); a[3] = (short)f2bf(f0.w);
    a[4] = (short)f2bf(f1.x); a[5] = (short)f2bf(f1.y);
    a[6] = (short)f2bf(f1.z); a[7] = (short)f2bf(f1.w);
    qa[s] = a;
  }

  f32x4 o[8];
#pragma unroll
  for (int dt = 0; dt < 8; ++dt) o[dt] = (f32x4){0.f, 0.f, 0.f, 0.f};
  float m[4], lsum[4];
#pragma unroll
  for (int r = 0; r < 4; ++r) { m[r] = -1e30f; lsum[r] = 0.f; }

  const float sc = 0.08838834764831845f * 1.4426950408889634f;  // 1/sqrt(128) * log2(e)

  const size_t krs = (size_t)NB * NHK * DH;   // 2048 floats between kv rows
  const float* kb = K + ((size_t)b * NHK + kh) * DH;
  const float* vb = V + ((size_t)b * NHK + kh) * DH;

  const int nt = qt + 1;

  for (int it = 0; it < nt; ++it) {
    const int kv0 = it * KVBLK;
    __syncthreads();
    // ---- stage K tile (row-contiguous mapping: perfect coalescing) ----
    {
      const int c  = tid & 31;          // float4 index within a 512B row
      const int r0 = tid >> 5;          // 0..7
#pragma unroll
      for (int j = 0; j < 8; ++j) {
        const int kvr = r0 + 8 * j;
        float4 f = *(const float4*)(kb + (size_t)(kv0 + kvr) * krs + 4 * c);
        bf16x4 pk;
        pk[0] = (short)f2bf(f.x); pk[1] = (short)f2bf(f.y);
        pk[2] = (short)f2bf(f.z); pk[3] = (short)f2bf(f.w);
        *(bf16x4*)((char*)Klds + kvr * 256 + ((c * 8) ^ ((kvr & 7) << 4))) = pk;
      }
      // ---- stage V transposed (kv-per-lane mapping: conflict-free LDS writes) ----
      const int kvr = tid & 63;
      const int dg  = tid >> 6;         // 0..3
#pragma unroll
      for (int j = 0; j < 8; ++j) {
        const int d0 = dg * 32 + 4 * j;
        float4 f = *(const float4*)(vb + (size_t)(kv0 + kvr) * krs + d0);
        Vt[(d0 + 0) * VSTR + kvr] = f2bf(f.x);
        Vt[(d0 + 1) * VSTR + kvr] = f2bf(f.y);
        Vt[(d0 + 2) * VSTR + kvr] = f2bf(f.z);
        Vt[(d0 + 3) * VSTR + kvr] = f2bf(f.w);
      }
    }
    __syncthreads();

    {
      // ---- QK^T: S[16 q][64 k] per wave ----
      f32x4 acc[4];
#pragma unroll
      for (int c = 0; c < 4; ++c) acc[c] = (f32x4){0.f, 0.f, 0.f, 0.f};
#pragma unroll
      for (int s = 0; s < 4; ++s) {
        const int cb = 64 * s + 16 * g;
#pragma unroll
        for (int c = 0; c < 4; ++c) {
          const int row = 16 * c + l15;
          bf16x8 bfr = *(const bf16x8*)((char*)Klds + row * 256 + (cb ^ ((row & 7) << 4)));
          acc[c] = __builtin_amdgcn_mfma_f32_16x16x32_bf16(qa[s], bfr, acc[c], 0, 0, 0);
        }
      }
      // ---- masked online softmax (wave-parallel, exp2 domain) ----
      const bool domask = (kv0 + KVBLK - 1 > qw);
      float t[4][4], pm[4];
#pragma unroll
      for (int r = 0; r < 4; ++r) {
        const int qr = qw + 4 * g + r;
        float v0 = acc[0][r] * sc, v1 = acc[1][r] * sc;
        float v2 = acc[2][r] * sc, v3 = acc[3][r] * sc;
        if (domask) {
          if (kv0 + 0  + l15 > qr) v0 = -1e30f;
          if (kv0 + 16 + l15 > qr) v1 = -1e30f;
          if (kv0 + 32 + l15 > qr) v2 = -1e30f;
          if (kv0 + 48 + l15 > qr) v3 = -1e30f;
        }
        t[0][r] = v0; t[1][r] = v1; t[2][r] = v2; t[3][r] = v3;
        pm[r] = fmaxf(fmaxf(v0, v1), fmaxf(v2, v3));
      }
#pragma unroll
      for (int off = 1; off <= 8; off <<= 1)
#pragma unroll
        for (int r = 0; r < 4; ++r)
          pm[r] = fmaxf(pm[r], __shfl_xor(pm[r], off));
      float fr[4], ps[4];
#pragma unroll
      for (int r = 0; r < 4; ++r) {
        const float mn = fmaxf(m[r], pm[r]);
        fr[r] = exp2f(m[r] - mn);
        m[r] = mn;
        float p0 = exp2f(t[0][r] - mn), p1 = exp2f(t[1][r] - mn);
        float p2 = exp2f(t[2][r] - mn), p3 = exp2f(t[3][r] - mn);
        t[0][r] = p0; t[1][r] = p1; t[2][r] = p2; t[3][r] = p3;
        ps[r] = (p0 + p1) + (p2 + p3);
      }
#pragma unroll
      for (int off = 1; off <= 8; off <<= 1)
#pragma unroll
        for (int r = 0; r < 4; ++r)
          ps[r] += __shfl_xor(ps[r], off);
#pragma unroll
      for (int r = 0; r < 4; ++r) lsum[r] = lsum[r] * fr[r] + ps[r];
#pragma unroll
      for (int dt = 0; dt < 8; ++dt)
#pragma unroll
        for (int r = 0; r < 4; ++r) o[dt][r] *= fr[r];
      // ---- P -> bf16 -> wave-private LDS (transpose to A-fragment layout) ----
      unsigned short* pw = &Plds[w][0];
#pragma unroll
      for (int c = 0; c < 4; ++c)
#pragma unroll
        for (int r = 0; r < 4; ++r)
          pw[(4 * g + r) * PSTR + 16 * c + l15] = f2bf(t[c][r]);
      // ---- PV: O[16 q][128 d] += P[16][64] * V[64][128] ----
#pragma unroll
      for (int ks = 0; ks < 2; ++ks) {
        bf16x8 pa = *(const bf16x8*)((char*)pw + l15 * (PSTR * 2) + 64 * ks + 16 * g);
#pragma unroll
        for (int dt = 0; dt < 8; ++dt) {
          bf16x8 vfr = *(const bf16x8*)((char*)Vt + (16 * dt + l15) * (VSTR * 2) + 64 * ks + 16 * g);
          o[dt] = __builtin_amdgcn_mfma_f32_16x16x32_bf16(pa, vfr, o[dt], 0, 0, 0);
        }
      }
    }
  }

  // ---- epilogue: normalize and store fp32 [s, b, h*d] ----
  float rl[4];
#pragma unroll
  for (int r = 0; r < 4; ++r) rl[r] = 1.0f / lsum[r];
  float* ob = O + ((size_t)b * NHQ + h) * DH;
#pragma unroll
  for (int dt = 0; dt < 8; ++dt) {
#pragma unroll
    for (int r = 0; r < 4; ++r) {
      const int sq = qb + 16 * w + 4 * g + r;
      ob[(size_t)sq * (NB * NHQ * DH) + 16 * dt + l15] = o[dt][r] * rl[r];
    }
  }
}

extern "C" void kernel_launch(void* const* d_in, const int* in_sizes, int n_in,
                              void* d_out, int out_size, void* d_ws, size_t ws_size,
                              hipStream_t stream) {
  const float* Q = (const float*)d_in[0];
  const float* K = (const float*)d_in[1];
  const float* V = (const float*)d_in[2];
  float* Out = (float*)d_out;
  dim3 grid(SLEN / QBLK, NB * NHQ);
  fattn_fwd<<<grid, 256, 0, stream>>>(Q, K, V, Out);
}

// Round 2
// 360.484 us; speedup vs baseline: 1.1725x; 1.1725x over previous
//
#include <hip/hip_runtime.h>

#define SLEN 2048
#define NB 2
#define NHQ 32
#define NHK 8
#define DH 128
#define QBLK 64
#define KVBLK 64
#define NT (SLEN / KVBLK)
#define NWAVES 4
#define PSTR 72      // P row stride in bf16 elems (144B)
#define TILE_B (KVBLK * DH * 2)   // 16384 bytes per staged tile image

typedef float  f32x4  __attribute__((ext_vector_type(4)));
typedef short  bf16x8 __attribute__((ext_vector_type(8)));

__device__ __forceinline__ unsigned short f2bf(float f) {
  union { float f; unsigned int u; } v; v.f = f;
  return (unsigned short)((v.u + 0x7fffu + ((v.u >> 16) & 1u)) >> 16);
}

// async global->LDS, 16B per lane. LDS dest must be wave-uniform; HW adds lane*16.
#define GLOAD16(g, l)                                                                   \
  __builtin_amdgcn_global_load_lds(                                                    \
      (const __attribute__((address_space(1))) unsigned int*)(g),                      \
      (__attribute__((address_space(3))) unsigned int*)(l), 16, 0, 0)

// ---------------- prep: fp32 K/V -> bf16 pre-swizzled LDS tile images in ws ---------
// K image per (bh,tile): [kv=64 rows of 256B], byte pos p in row holds K[kv][(p^((kv&7)<<4))/2 ..]
// V image per (bh,tile): [d=128 rows of 128B], byte pos p in row holds V[kv=(p^((d&7)<<4))/2 ..][d]
__global__ __launch_bounds__(256)
void prep_kv(const float* __restrict__ K, const float* __restrict__ V,
             unsigned short* __restrict__ W) {
  const int tile = blockIdx.x;
  const int bh   = blockIdx.y;          // b*NHK + kh
  const int tid  = threadIdx.x;
  const size_t krs = (size_t)NB * NHK * DH;
  const float* kb = K + (size_t)bh * DH + (size_t)tile * KVBLK * krs;
  const float* vb = V + (size_t)bh * DH + (size_t)tile * KVBLK * krs;
  unsigned short* kd = W + ((size_t)bh * NT + tile) * (KVBLK * DH);
  unsigned short* vd = W + (size_t)NB * NHK * NT * (KVBLK * DH)
                         + ((size_t)bh * NT + tile) * (KVBLK * DH);
#pragma unroll
  for (int i = 0; i < 4; ++i) {
    const int cid  = tid + 256 * i;
    const int row  = cid >> 4;                 // kv row
    const int cpos = (cid & 15) << 4;          // dst byte pos
    const int cb   = cpos ^ ((row & 7) << 4);  // src byte col
    const float* s = kb + (size_t)row * krs + (cb >> 1);
    float4 f0 = *(const float4*)s;
    float4 f1 = *(const float4*)(s + 4);
    bf16x8 a;
    a[0]=(short)f2bf(f0.x); a[1]=(short)f2bf(f0.y); a[2]=(short)f2bf(f0.z); a[3]=(short)f2bf(f0.w);
    a[4]=(short)f2bf(f1.x); a[5]=(short)f2bf(f1.y); a[6]=(short)f2bf(f1.z); a[7]=(short)f2bf(f1.w);
    *(bf16x8*)((char*)kd + row * 256 + cpos) = a;
  }
#pragma unroll
  for (int i = 0; i < 4; ++i) {
    const int cid  = tid + 256 * i;
    const int d    = cid >> 3;
    const int cpos = (cid & 7) << 4;
    const int kb2  = cpos ^ ((d & 7) << 4);
    const int kv   = kb2 >> 1;
    bf16x8 a;
#pragma unroll
    for (int j = 0; j < 8; ++j) a[j] = (short)f2bf(vb[(size_t)(kv + j) * krs + d]);
    *(bf16x8*)((char*)vd + d * 128 + cpos) = a;
  }
}

// ---------------- main attention kernel ----------------
__global__ __launch_bounds__(256, 2)
void fattn_fwd(const float* __restrict__ Q, const unsigned short* __restrict__ KW,
               const unsigned short* __restrict__ VW, float* __restrict__ O) {
  const int tid  = threadIdx.x;
  const int w    = tid >> 6;
  const int lane = tid & 63;
  const int l15  = lane & 15;
  const int g    = lane >> 4;

  const int qt = (int)gridDim.x - 1 - (int)blockIdx.x;  // big tiles dispatch first
  const int hb = blockIdx.y;
  const int b  = hb >> 5;
  const int h  = hb & (NHQ - 1);
  const int kh = h >> 2;

  const int qb = qt * QBLK;
  const int qw = qb + 16 * w;

  __shared__ alignas(16) unsigned short Kbuf[2][KVBLK * DH];   // 2x16KB
  __shared__ alignas(16) unsigned short Vbuf[2][DH * KVBLK];   // 2x16KB
  __shared__ alignas(16) unsigned short Plds[NWAVES][16 * PSTR];

  const char* kws = (const char*)(KW + ((size_t)(b * NHK + kh) * NT) * (KVBLK * DH));
  const char* vws = (const char*)(VW + ((size_t)(b * NHK + kh) * NT) * (KVBLK * DH));

  // ---- Q fragments: fp32 -> bf16 in reg, once per block ----
  const float* qp = Q + ((size_t)((qb + 16 * w + l15) * NB + b) * NHQ + h) * DH;
  bf16x8 qa[4];
#pragma unroll
  for (int s = 0; s < 4; ++s) {
    const float* p = qp + 32 * s + 8 * g;
    float4 f0 = *(const float4*)(p);
    float4 f1 = *(const float4*)(p + 4);
    bf16x8 a;
    a[0]=(short)f2bf(f0.x); a[1]=(short)f2bf(f0.y); a[2]=(short)f2bf(f0.z); a[3]=(short)f2bf(f0.w);
    a[4]=(short)f2bf(f1.x); a[5]=(short)f2bf(f1.y); a[6]=(short)f2bf(f1.z); a[7]=(short)f2bf(f1.w);
    qa[s] = a;
  }

  f32x4 o[8];
#pragma unroll
  for (int dt = 0; dt < 8; ++dt) o[dt] = (f32x4){0.f, 0.f, 0.f, 0.f};
  float m[4], lsum[4];
#pragma unroll
  for (int r = 0; r < 4; ++r) { m[r] = -1e30f; lsum[r] = 0.f; }

  const float sc = 0.08838834764831845f * 1.4426950408889634f;  // 1/sqrt(128)*log2(e)
  const int nt = qt + 1;

  // ---- prologue: stage tile 0 into buffer 0 ----
#pragma unroll
  for (int i = 0; i < 4; ++i) {
    const int off = i * 4096 + w * 1024;
    GLOAD16(kws + off + (lane << 4), (char*)Kbuf[0] + off);
    GLOAD16(vws + off + (lane << 4), (char*)Vbuf[0] + off);
  }

  int cur = 0;
  for (int it = 0; it < nt; ++it) {
    if (it + 1 < nt) {
      const char* ks = kws + (size_t)(it + 1) * TILE_B;
      const char* vs = vws + (size_t)(it + 1) * TILE_B;
#pragma unroll
      for (int i = 0; i < 4; ++i) {
        const int off = i * 4096 + w * 1024;
        GLOAD16(ks + off + (lane << 4), (char*)Kbuf[cur ^ 1] + off);
        GLOAD16(vs + off + (lane << 4), (char*)Vbuf[cur ^ 1] + off);
      }
      asm volatile("s_waitcnt vmcnt(8)" ::: "memory");  // current tile's 8 loads done
    } else {
      asm volatile("s_waitcnt vmcnt(0)" ::: "memory");
    }
    __builtin_amdgcn_s_barrier();
    asm volatile("" ::: "memory");

    const unsigned short* Kc = Kbuf[cur];
    const unsigned short* Vc = Vbuf[cur];
    const int kv0 = it * KVBLK;

    // ---- QK^T: S[16 q][64 k] per wave ----
    f32x4 acc[4];
#pragma unroll
    for (int c = 0; c < 4; ++c) acc[c] = (f32x4){0.f, 0.f, 0.f, 0.f};
#pragma unroll
    for (int s = 0; s < 4; ++s) {
      const int cb = 64 * s + 16 * g;
#pragma unroll
      for (int c = 0; c < 4; ++c) {
        const int row = 16 * c + l15;
        bf16x8 bfr = *(const bf16x8*)((const char*)Kc + row * 256 + (cb ^ ((row & 7) << 4)));
        acc[c] = __builtin_amdgcn_mfma_f32_16x16x32_bf16(qa[s], bfr, acc[c], 0, 0, 0);
      }
    }

    // ---- masked online softmax (wave-parallel, exp2 domain, defer-max) ----
    const bool domask = (kv0 + KVBLK - 1 > qw);
    float t[4][4], pm[4];
#pragma unroll
    for (int r = 0; r < 4; ++r) {
      const int qr = qw + 4 * g + r;
      float v0 = acc[0][r] * sc, v1 = acc[1][r] * sc;
      float v2 = acc[2][r] * sc, v3 = acc[3][r] * sc;
      if (domask) {
        if (kv0 + 0  + l15 > qr) v0 = -1e30f;
        if (kv0 + 16 + l15 > qr) v1 = -1e30f;
        if (kv0 + 32 + l15 > qr) v2 = -1e30f;
        if (kv0 + 48 + l15 > qr) v3 = -1e30f;
      }
      t[0][r] = v0; t[1][r] = v1; t[2][r] = v2; t[3][r] = v3;
      pm[r] = fmaxf(fmaxf(v0, v1), fmaxf(v2, v3));
    }
#pragma unroll
    for (int off = 1; off <= 8; off <<= 1)
#pragma unroll
      for (int r = 0; r < 4; ++r)
        pm[r] = fmaxf(pm[r], __shfl_xor(pm[r], off));

    bool sk = true;
#pragma unroll
    for (int r = 0; r < 4; ++r) sk &= (pm[r] <= m[r] + 11.0f);
    if (!__all((int)sk)) {
#pragma unroll
      for (int r = 0; r < 4; ++r) {
        const float mn = fmaxf(m[r], pm[r]);
        const float fr = exp2f(m[r] - mn);
        m[r] = mn;
        lsum[r] *= fr;
#pragma unroll
        for (int dt = 0; dt < 8; ++dt) o[dt][r] *= fr;
      }
    }
    float ps[4];
#pragma unroll
    for (int r = 0; r < 4; ++r) {
      float p0 = exp2f(t[0][r] - m[r]), p1 = exp2f(t[1][r] - m[r]);
      float p2 = exp2f(t[2][r] - m[r]), p3 = exp2f(t[3][r] - m[r]);
      t[0][r] = p0; t[1][r] = p1; t[2][r] = p2; t[3][r] = p3;
      ps[r] = (p0 + p1) + (p2 + p3);
    }
#pragma unroll
    for (int off = 1; off <= 8; off <<= 1)
#pragma unroll
      for (int r = 0; r < 4; ++r)
        ps[r] += __shfl_xor(ps[r], off);
#pragma unroll
    for (int r = 0; r < 4; ++r) lsum[r] += ps[r];

    // ---- P -> bf16 -> wave-private LDS (transpose to A-fragment layout) ----
    unsigned short* pw = &Plds[w][0];
#pragma unroll
    for (int c = 0; c < 4; ++c)
#pragma unroll
      for (int r = 0; r < 4; ++r)
        pw[(4 * g + r) * PSTR + 16 * c + l15] = f2bf(t[c][r]);

    // ---- PV: O[16 q][128 d] += P[16][64] * V[64][128] ----
#pragma unroll
    for (int ks2 = 0; ks2 < 2; ++ks2) {
      bf16x8 pa = *(const bf16x8*)((const char*)pw + l15 * (PSTR * 2) + 64 * ks2 + 16 * g);
#pragma unroll
      for (int dt = 0; dt < 8; ++dt) {
        const int d = 16 * dt + l15;
        bf16x8 vfr = *(const bf16x8*)((const char*)Vc + d * 128 + ((64 * ks2 + 16 * g) ^ ((d & 7) << 4)));
        o[dt] = __builtin_amdgcn_mfma_f32_16x16x32_bf16(pa, vfr, o[dt], 0, 0, 0);
      }
    }

    asm volatile("" ::: "memory");
    __builtin_amdgcn_s_barrier();   // all reads of buf[cur] done before next overwrite
    cur ^= 1;
  }

  // ---- epilogue: normalize and store fp32 [s, b, h*d] ----
  float rl[4];
#pragma unroll
  for (int r = 0; r < 4; ++r) rl[r] = 1.0f / lsum[r];
  float* ob = O + ((size_t)b * NHQ + h) * DH;
#pragma unroll
  for (int dt = 0; dt < 8; ++dt) {
#pragma unroll
    for (int r = 0; r < 4; ++r) {
      const int sq = qb + 16 * w + 4 * g + r;
      ob[(size_t)sq * (NB * NHQ * DH) + 16 * dt + l15] = o[dt][r] * rl[r];
    }
  }
}

extern "C" void kernel_launch(void* const* d_in, const int* in_sizes, int n_in,
                              void* d_out, int out_size, void* d_ws, size_t ws_size,
                              hipStream_t stream) {
  const float* Q = (const float*)d_in[0];
  const float* K = (const float*)d_in[1];
  const float* V = (const float*)d_in[2];
  float* Out = (float*)d_out;
  unsigned short* W = (unsigned short*)d_ws;   // needs 16.78 MB

  dim3 pgrid(NT, NB * NHK);
  prep_kv<<<pgrid, 256, 0, stream>>>(K, V, W);

  const unsigned short* KW = W;
  const unsigned short* VW = W + (size_t)NB * NHK * NT * (KVBLK * DH);
  dim3 grid(SLEN / QBLK, NB * NHQ);
  fattn_fwd<<<grid, 256, 0, stream>>>(Q, KW, VW, Out);
}

// Round 3
// 245.644 us; speedup vs baseline: 1.7206x; 1.4675x over previous
//
#include <hip/hip_runtime.h>

#define SLEN 2048
#define NB 2
#define NHQ 32
#define NHK 8
#define DH 128
#define QBLK 128
#define KVBLK 64
#define NT (SLEN / KVBLK)
#define NWAVES 8
#define TILE_B (KVBLK * DH * 2)   // 16384 bytes per staged tile image

typedef float  f32x4  __attribute__((ext_vector_type(4)));
typedef short  bf16x8 __attribute__((ext_vector_type(8)));

__device__ __forceinline__ unsigned short f2bf(float f) {
  union { float f; unsigned int u; } v; v.f = f;
  return (unsigned short)((v.u + 0x7fffu + ((v.u >> 16) & 1u)) >> 16);
}

// async global->LDS, 16B per lane. LDS dest is wave-uniform; HW adds lane*16.
#define GLOAD16(g, l)                                                                   \
  __builtin_amdgcn_global_load_lds(                                                    \
      (const __attribute__((address_space(1))) unsigned int*)(g),                      \
      (__attribute__((address_space(3))) unsigned int*)(l), 16, 0, 0)

// ---------------- prep: fp32 K/V -> bf16 pre-swizzled LDS tile images in ws ---------
// K image per (bh,tile): [kv=64 rows of 256B], byte p in row holds K[kv][(p^((kv&7)<<4))/2..]
// V image per (bh,tile): [d=128 rows of 128B], byte p in row holds V[kv=(p^((d&7)<<4))/2..][d]
__global__ __launch_bounds__(256)
void prep_kv(const float* __restrict__ K, const float* __restrict__ V,
             unsigned short* __restrict__ W) {
  const int tile = blockIdx.x;
  const int bh   = blockIdx.y;          // b*NHK + kh
  const int tid  = threadIdx.x;
  const size_t krs = (size_t)NB * NHK * DH;
  const float* kb = K + (size_t)bh * DH + (size_t)tile * KVBLK * krs;
  const float* vb = V + (size_t)bh * DH + (size_t)tile * KVBLK * krs;
  unsigned short* kd = W + ((size_t)bh * NT + tile) * (KVBLK * DH);
  unsigned short* vd = W + (size_t)NB * NHK * NT * (KVBLK * DH)
                         + ((size_t)bh * NT + tile) * (KVBLK * DH);
#pragma unroll
  for (int i = 0; i < 4; ++i) {
    const int cid  = tid + 256 * i;
    const int row  = cid >> 4;                 // kv row
    const int cpos = (cid & 15) << 4;          // dst byte pos
    const int cb   = cpos ^ ((row & 7) << 4);  // src byte col
    const float* s = kb + (size_t)row * krs + (cb >> 1);
    float4 f0 = *(const float4*)s;
    float4 f1 = *(const float4*)(s + 4);
    bf16x8 a;
    a[0]=(short)f2bf(f0.x); a[1]=(short)f2bf(f0.y); a[2]=(short)f2bf(f0.z); a[3]=(short)f2bf(f0.w);
    a[4]=(short)f2bf(f1.x); a[5]=(short)f2bf(f1.y); a[6]=(short)f2bf(f1.z); a[7]=(short)f2bf(f1.w);
    *(bf16x8*)((char*)kd + row * 256 + cpos) = a;
  }
#pragma unroll
  for (int i = 0; i < 4; ++i) {
    const int cid  = tid + 256 * i;
    const int d    = cid >> 3;
    const int cpos = (cid & 7) << 4;
    const int kb2  = cpos ^ ((d & 7) << 4);
    const int kv   = kb2 >> 1;
    bf16x8 a;
#pragma unroll
    for (int j = 0; j < 8; ++j) a[j] = (short)f2bf(vb[(size_t)(kv + j) * krs + d]);
    *(bf16x8*)((char*)vd + d * 128 + cpos) = a;
  }
}

// ---------------- main attention kernel (8 waves, swapped-QK^T, in-reg softmax) ------
__global__ __launch_bounds__(512, 4)
void fattn_fwd(const float* __restrict__ Q, const unsigned short* __restrict__ KW,
               const unsigned short* __restrict__ VW, float* __restrict__ O) {
  const int tid  = threadIdx.x;
  const int w    = tid >> 6;        // wave 0..7
  const int lane = tid & 63;
  const int l15  = lane & 15;
  const int g    = lane >> 4;       // 16-lane group 0..3

  const int qt = (int)gridDim.x - 1 - (int)blockIdx.x;  // big tiles dispatch first
  const int hb = blockIdx.y;
  const int b  = hb >> 5;
  const int h  = hb & (NHQ - 1);
  const int kh = h >> 2;

  const int qb   = qt * QBLK;
  const int qw   = qb + 16 * w;     // wave's first q row
  const int qrow = qw + l15;        // this lane's q (output column)

  __shared__ alignas(16) unsigned short Kbuf[2][KVBLK * DH];   // 2x16KB
  __shared__ alignas(16) unsigned short Vbuf[2][DH * KVBLK];   // 2x16KB

  const char* kws = (const char*)(KW + ((size_t)(b * NHK + kh) * NT) * (KVBLK * DH));
  const char* vws = (const char*)(VW + ((size_t)(b * NHK + kh) * NT) * (KVBLK * DH));

  // ---- Q fragments: fp32 -> bf16 in reg, once per block ----
  const float* qp = Q + ((size_t)(qrow * NB + b) * NHQ + h) * DH;
  bf16x8 qa[4];
#pragma unroll
  for (int s = 0; s < 4; ++s) {
    const float* p = qp + 32 * s + 8 * g;
    float4 f0 = *(const float4*)(p);
    float4 f1 = *(const float4*)(p + 4);
    bf16x8 a;
    a[0]=(short)f2bf(f0.x); a[1]=(short)f2bf(f0.y); a[2]=(short)f2bf(f0.z); a[3]=(short)f2bf(f0.w);
    a[4]=(short)f2bf(f1.x); a[5]=(short)f2bf(f1.y); a[6]=(short)f2bf(f1.z); a[7]=(short)f2bf(f1.w);
    qa[s] = a;
  }

  f32x4 o[8];
#pragma unroll
  for (int dt = 0; dt < 8; ++dt) o[dt] = (f32x4){0.f, 0.f, 0.f, 0.f};
  float m = -1e30f, lsum = 0.f;

  const float sc = 0.08838834764831845f * 1.4426950408889634f;  // 1/sqrt(128)*log2(e)
  const int nt = 2 * qt + 2;

  // ---- prologue: stage tile 0 into buffer 0 (4 loads/thread, 8 waves cover 32KB) ----
#pragma unroll
  for (int i = 0; i < 2; ++i) {
    const int off = i * 8192 + w * 1024;
    GLOAD16(kws + off + (lane << 4), (char*)Kbuf[0] + off);
    GLOAD16(vws + off + (lane << 4), (char*)Vbuf[0] + off);
  }

  int cur = 0;
  for (int it = 0; it < nt; ++it) {
    if (it + 1 < nt) {
      const char* ks = kws + (size_t)(it + 1) * TILE_B;
      const char* vs = vws + (size_t)(it + 1) * TILE_B;
#pragma unroll
      for (int i = 0; i < 2; ++i) {
        const int off = i * 8192 + w * 1024;
        GLOAD16(ks + off + (lane << 4), (char*)Kbuf[cur ^ 1] + off);
        GLOAD16(vs + off + (lane << 4), (char*)Vbuf[cur ^ 1] + off);
      }
      asm volatile("s_waitcnt vmcnt(4)" ::: "memory");  // current tile's 4 loads done
    } else {
      asm volatile("s_waitcnt vmcnt(0)" ::: "memory");
    }
    __builtin_amdgcn_s_barrier();
    asm volatile("" ::: "memory");

    const unsigned short* Kc = Kbuf[cur];
    const unsigned short* Vc = Vbuf[cur];
    const int kv0 = it * KVBLK;

    if (kv0 <= qw + 15) {   // wave has unmasked work in this tile
      // ---- swapped QK^T: S^T[64 kv][16 q]; lane owns q=qrow, kv=16c+4g+r ----
      f32x4 acc[4];
#pragma unroll
      for (int c = 0; c < 4; ++c) acc[c] = (f32x4){0.f, 0.f, 0.f, 0.f};
#pragma unroll
      for (int s = 0; s < 4; ++s) {
        const int cb = 64 * s + 16 * g;
#pragma unroll
        for (int c = 0; c < 4; ++c) {
          const int row = 16 * c + l15;
          bf16x8 kfr = *(const bf16x8*)((const char*)Kc + row * 256 + (cb ^ ((row & 7) << 4)));
          acc[c] = __builtin_amdgcn_mfma_f32_16x16x32_bf16(kfr, qa[s], acc[c], 0, 0, 0);
        }
      }

      // ---- in-register masked online softmax (exp2 domain, defer-max) ----
      const bool domask = (kv0 + KVBLK - 1 > qw);
      float p[4][4];
      float pm = -1e30f;
#pragma unroll
      for (int c = 0; c < 4; ++c)
#pragma unroll
        for (int r = 0; r < 4; ++r) {
          float v = acc[c][r] * sc;
          if (domask) {
            const int kv = kv0 + 16 * c + 4 * g + r;
            v = (kv > qrow) ? -1e30f : v;
          }
          p[c][r] = v;
          pm = fmaxf(pm, v);
        }
      pm = fmaxf(pm, __shfl_xor(pm, 16));
      pm = fmaxf(pm, __shfl_xor(pm, 32));

      if (!__all((int)(pm <= m + 11.0f))) {
        const float mn = fmaxf(m, pm);
        const float fr = exp2f(m - mn);
        m = mn;
        lsum *= fr;
#pragma unroll
        for (int dt = 0; dt < 8; ++dt) o[dt] = o[dt] * fr;
      }
      float ps = 0.f;
#pragma unroll
      for (int c = 0; c < 4; ++c)
#pragma unroll
        for (int r = 0; r < 4; ++r) {
          const float e = exp2f(p[c][r] - m);
          p[c][r] = e;
          ps += e;
        }
      ps += __shfl_xor(ps, 16);
      ps += __shfl_xor(ps, 32);
      lsum += ps;

      // ---- pack P^T to bf16 pairs and redistribute to PV B-fragment layout ----
      unsigned int pk[4][2];
#pragma unroll
      for (int c = 0; c < 4; ++c)
#pragma unroll
        for (int rr = 0; rr < 2; ++rr)
          pk[c][rr] = (unsigned int)f2bf(p[c][2 * rr]) |
                      ((unsigned int)f2bf(p[c][2 * rr + 1]) << 16);

      int pa32[2][4];
      const bool hi = (g >= 2);
#pragma unroll
      for (int ks = 0; ks < 2; ++ks)
#pragma unroll
        for (int j = 0; j < 4; ++j) {
          const int srcl = (((2 * g + (j >> 1)) & 3) << 4) + l15;
          const int va = __shfl((int)pk[2 * ks][j & 1], srcl);
          const int vb2 = __shfl((int)pk[2 * ks + 1][j & 1], srcl);
          pa32[ks][j] = hi ? vb2 : va;
        }

      // ---- PV: O^T[128 d][16 q] += V^T[d][kv] * P^T[kv][q] ----
#pragma unroll
      for (int ks = 0; ks < 2; ++ks) {
        union { int u[4]; bf16x8 v; } pu;
        pu.u[0] = pa32[ks][0]; pu.u[1] = pa32[ks][1];
        pu.u[2] = pa32[ks][2]; pu.u[3] = pa32[ks][3];
        const bf16x8 pa = pu.v;
#pragma unroll
        for (int dt = 0; dt < 8; ++dt) {
          const int d = 16 * dt + l15;
          bf16x8 vfr = *(const bf16x8*)((const char*)Vc + d * 128 +
                                        ((64 * ks + 16 * g) ^ ((d & 7) << 4)));
          o[dt] = __builtin_amdgcn_mfma_f32_16x16x32_bf16(vfr, pa, o[dt], 0, 0, 0);
        }
      }
    }

    asm volatile("" ::: "memory");
    __builtin_amdgcn_s_barrier();   // all reads of buf[cur] done before overwrite
    cur ^= 1;
  }

  // ---- epilogue: normalize, store fp32 [s, b, h*d]; lane holds O[qrow][16dt+4g+r] ----
  const float rl = 1.0f / lsum;
  float* ob = O + ((size_t)b * NHQ + h) * DH + (size_t)qrow * (NB * NHQ * DH);
#pragma unroll
  for (int dt = 0; dt < 8; ++dt) {
    float4 st;
    st.x = o[dt][0] * rl; st.y = o[dt][1] * rl;
    st.z = o[dt][2] * rl; st.w = o[dt][3] * rl;
    *(float4*)(ob + 16 * dt + 4 * g) = st;
  }
}

extern "C" void kernel_launch(void* const* d_in, const int* in_sizes, int n_in,
                              void* d_out, int out_size, void* d_ws, size_t ws_size,
                              hipStream_t stream) {
  const float* Q = (const float*)d_in[0];
  const float* K = (const float*)d_in[1];
  const float* V = (const float*)d_in[2];
  float* Out = (float*)d_out;
  unsigned short* W = (unsigned short*)d_ws;   // needs 16.78 MB

  dim3 pgrid(NT, NB * NHK);
  prep_kv<<<pgrid, 256, 0, stream>>>(K, V, W);

  const unsigned short* KW = W;
  const unsigned short* VW = W + (size_t)NB * NHK * NT * (KVBLK * DH);
  dim3 grid(SLEN / QBLK, NB * NHQ);
  fattn_fwd<<<grid, 512, 0, stream>>>(Q, KW, VW, Out);
}